// Round 8
// baseline (266.205 us; speedup 1.0000x reference)
//
#include <hip/hip_runtime.h>
#include <hip/hip_bf16.h>

#define T 2048
#define HID 2048
#define NH 16
#define NKH 4
#define HD 128
#define GSZ 128

typedef __attribute__((ext_vector_type(8))) short short8;
typedef __attribute__((ext_vector_type(4))) float f32x4;

#define GLOAD16(gp, lp) __builtin_amdgcn_global_load_lds( \
    (const __attribute__((address_space(1))) void*)(gp), \
    (__attribute__((address_space(3))) void*)(lp), 16, 0, 0)

__device__ inline short f2b(float f) {
    unsigned int u = __float_as_uint(f);
    unsigned int r = (u + 0x7fffu + ((u >> 16) & 1u)) >> 16;
    return (short)r;
}
__device__ inline float b2f(unsigned short u) {
    return __uint_as_float((unsigned int)u << 16);
}

// ---------------- dequant: int4 GPTQ -> bf16 W^T [N][K] ----------------
__global__ __launch_bounds__(256) void dequant_kernel(
    const int* __restrict__ qw, const float* __restrict__ sc,
    const int* __restrict__ qz, short* __restrict__ Wt, int K, int N) {
    int tid = blockIdx.x * blockDim.x + threadIdx.x;
    int K8 = K >> 3;
    if (tid >= N * K8) return;
    int n = tid / K8;
    int k8 = tid - n * K8;
    int q32 = qw[k8 * N + n];
    int g = (k8 << 3) / GSZ;
    float scale = sc[g * N + n];
    int z = (qz[g * (N >> 3) + (n >> 3)] >> ((n & 7) * 4)) & 15;
    float zf = (float)(z + 1);
    short8 out;
#pragma unroll
    for (int kk = 0; kk < 8; kk++) {
        int q = (q32 >> (kk * 4)) & 15;
        out[kk] = f2b(scale * ((float)q - zf));
    }
    *reinterpret_cast<short8*>(&Wt[n * K + (k8 << 3)]) = out;
}

// ---------------- cast x f32 -> bf16 ----------------
__global__ __launch_bounds__(256) void cast_kernel(
    const float* __restrict__ x, short* __restrict__ xb, int n8) {
    int i = blockIdx.x * blockDim.x + threadIdx.x;
    if (i >= n8) return;
    const float4* xp = reinterpret_cast<const float4*>(x) + i * 2;
    float4 a = xp[0], b = xp[1];
    short8 o;
    o[0] = f2b(a.x); o[1] = f2b(a.y); o[2] = f2b(a.z); o[3] = f2b(a.w);
    o[4] = f2b(b.x); o[5] = f2b(b.y); o[6] = f2b(b.z); o[7] = f2b(b.w);
    reinterpret_cast<short8*>(xb)[i] = o;
}

// ------- split-K GEMM: C[M,N] f32 += A[M,K]bf16 * Bt[N,K]bf16^T (atomic) -------
// blockIdx.z picks K-range [z*klen, (z+1)*klen). C must be zeroed before launch.
// f32 atomic adds from 0 are order-commutative -> deterministic within threshold.
#define BM 128
#define BN 128
#define BK 64

__global__ __launch_bounds__(256) void gemm_bt_splitk(
    const short* __restrict__ A, const short* __restrict__ Bt,
    float* __restrict__ C, int M, int N, int K, int klen) {
    __shared__ short As[BM * BK];
    __shared__ short Bs[BN * BK];
    const int t = threadIdx.x;
    const int lane = t & 63;
    const int w = t >> 6;
    const int bm = blockIdx.y * BM;
    const int bn = blockIdx.x * BN;
    const int kbase = blockIdx.z * klen;
    const int wm = (w >> 1) * 64;
    const int wn = (w & 1) * 64;
    const int lr = lane & 15;
    const int lk = (lane >> 4) * 8;
    f32x4 acc[4][4] = {};
    for (int k0 = kbase; k0 < kbase + klen; k0 += BK) {
        __syncthreads();
#pragma unroll
        for (int i = 0; i < 4; i++) {
            int c = w * 4 + i;
            int grow = c * 8 + (lane >> 3);
            int gcol = (lane & 7) * 8;
            GLOAD16(&A[(bm + grow) * K + k0 + gcol], &As[c * 512]);
            GLOAD16(&Bt[(bn + grow) * K + k0 + gcol], &Bs[c * 512]);
        }
        __syncthreads();
#pragma unroll
        for (int kc = 0; kc < 2; kc++) {
            short8 af[4], bf[4];
#pragma unroll
            for (int m = 0; m < 4; m++)
                af[m] = *reinterpret_cast<const short8*>(
                    &As[(wm + m * 16 + lr) * BK + kc * 32 + lk]);
#pragma unroll
            for (int n = 0; n < 4; n++)
                bf[n] = *reinterpret_cast<const short8*>(
                    &Bs[(wn + n * 16 + lr) * BK + kc * 32 + lk]);
#pragma unroll
            for (int m = 0; m < 4; m++)
#pragma unroll
                for (int n = 0; n < 4; n++)
                    acc[m][n] = __builtin_amdgcn_mfma_f32_16x16x32_bf16(
                        af[m], bf[n], acc[m][n], 0, 0, 0);
        }
    }
    const int rowb = bm + wm + (lane >> 4) * 4;
    const int colb = bn + wn + lr;
#pragma unroll
    for (int m = 0; m < 4; m++)
#pragma unroll
        for (int n = 0; n < 4; n++)
#pragma unroll
            for (int rr = 0; rr < 4; rr++)
                unsafeAtomicAdd(&C[(rowb + m * 16 + rr) * N + colb + n * 16],
                                acc[m][n][rr]);
}

// ---------------- rmsnorm + rope ----------------
__global__ __launch_bounds__(128) void normrope_kernel(
    const float* __restrict__ qkv, const float* __restrict__ qw,
    const float* __restrict__ kw, const int* __restrict__ pos,
    short* __restrict__ Qb, short* __restrict__ Kb) {
    int tt = blockIdx.x;
    int hh = blockIdx.y;
    int d = threadIdx.x;
    bool isq = hh < NH;
    int h = isq ? hh : hh - NH;
    int off = isq ? h * HD : HID + h * HD;
    float x = qkv[tt * 3072 + off + d];
    float ss = x * x;
#pragma unroll
    for (int mask = 1; mask < 64; mask <<= 1) ss += __shfl_xor(ss, mask, 64);
    __shared__ float red[2];
    __shared__ float vals[HD];
    if ((d & 63) == 0) red[d >> 6] = ss;
    __syncthreads();
    float tot = red[0] + red[1];
    float r = rsqrtf(tot * (1.0f / HD) + 1e-6f);
    float wv = isq ? qw[d] : kw[d];
    float xn = x * r * wv;
    vals[d] = xn;
    __syncthreads();
    int p = pos[tt];
    int i = d & 63;
    float inv = exp2f(-(float)i * (13.287712379549449f / 64.0f));
    float ang = (float)p * inv;
    float c, s;
    sincosf(ang, &s, &c);
    float other = vals[d ^ 64];
    float out = (d < 64) ? (xn * c - other * s) : (xn * c + other * s);
    if (isq) Qb[tt * HID + h * HD + d] = f2b(out);
    else     Kb[(h * T + tt) * HD + d] = f2b(out);
}

// ---------------- V transpose: qkv f32 -> Vt[KH][HD][T] bf16 ----------------
__global__ __launch_bounds__(256) void vtrans_kernel(
    const float* __restrict__ qkv, short* __restrict__ Vt) {
    __shared__ float tile[32][33];
    int h = blockIdx.z;
    int d0 = blockIdx.y * 32;
    int t0 = blockIdx.x * 32;
    int tx = threadIdx.x & 31;
    int ty = threadIdx.x >> 5;
#pragma unroll
    for (int i = 0; i < 32; i += 8)
        tile[ty + i][tx] = qkv[(t0 + ty + i) * 3072 + 2560 + h * HD + d0 + tx];
    __syncthreads();
#pragma unroll
    for (int i = 0; i < 32; i += 8)
        Vt[(h * HD + d0 + ty + i) * T + t0 + tx] = f2b(tile[tx][ty + i]);
}

// ---------------- flash attention, split-K, FIXED-MAX softmax ----------------
// RMSNorm(w=1) bounds ||q||,||k|| <= sqrt(128); RoPE is a rotation ->
// every score s = q.k/sqrt(128) satisfies |s| <= sqrt(128) ~ 11.4 < 12.
// P = exp(s - 12): no running max, no rescale, no max reduction.
// Row-sum l via one extra MFMA against all-ones B. Combine: O = sum(U)/sum(l).
#define QB 64
#define KVB 32
#define NSPLIT 4
#define PLD 40   // P row stride in elems (80 B: 16B-aligned b128 rows)

__global__ __launch_bounds__(256) void attn_split_kernel(
    const short* __restrict__ Qb, const short* __restrict__ Kb,
    const short* __restrict__ Vt, unsigned short* __restrict__ U,
    float2* __restrict__ stats) {
    __shared__ short Ks[2][KVB * HD];   // [32][128], chunk-swizzled
    __shared__ short Vs[2][HD * KVB];   // [128][32], linear
    __shared__ short P[4][16 * PLD];
    const int t = threadIdx.x;
    const int lane = t & 63;
    const int w = t >> 6;
    const int h = blockIdx.y;
    const int sp = blockIdx.z;
    const int kvh = h >> 2;
    int bx = blockIdx.x;
    const int qt = (bx & 1) ? ((int)gridDim.x - 1 - (bx >> 1)) : (bx >> 1);
    const int qb0 = qt * QB;
    const int lr = lane & 15;
    const int g = lane >> 4;
    const int lk = g * 8;
    const int rowb = qb0 + w * 16 + g * 4;
    const int nt = (qt + 1) * 2;               // total 32-key tiles (causal window)
    const int len = (nt + NSPLIT - 1) / NSPLIT;
    int jt0 = sp * len; if (jt0 > nt) jt0 = nt;
    int jt1 = jt0 + len; if (jt1 > nt) jt1 = nt;

    f32x4 oacc[8] = {};
    f32x4 lacc = {};                           // row-sums via ones-MFMA
    const float scale = 0.08838834764831845f;  // 1/sqrt(128)
    short8 kOnes;
#pragma unroll
    for (int kk = 0; kk < 8; kk++) kOnes[kk] = (short)0x3F80;  // bf16 1.0

    if (jt0 < jt1) {
        short8 qf[4];
        {
            const short* qp = Qb + (qb0 + w * 16 + lr) * HID + h * HD + lk;
#pragma unroll
            for (int kk = 0; kk < 4; kk++)
                qf[kk] = *reinterpret_cast<const short8*>(qp + kk * 32);
        }
        const short* kgb = Kb + (size_t)(kvh * T) * HD;
        const short* vgb = Vt + (size_t)(kvh * HD) * T;
        const int kr4 = lane >> 4;            // K stage: row within 4-row group
        const int vr16 = lane >> 2;           // V stage: row within 16-row group

        // prologue: stage tile jt0 into buf 0
        {
            const int key0 = jt0 * KVB;
#pragma unroll
            for (int i = 0; i < 2; i++) {
                int c2 = w * 2 + i;
                int r7 = ((c2 & 1) << 2) | kr4;
                int kcol = ((lane & 15) ^ r7) * 8;
                GLOAD16(kgb + (key0 + c2 * 4 + kr4) * HD + kcol, &Ks[0][c2 * 512]);
                GLOAD16(vgb + (c2 * 16 + vr16) * T + key0 + (lane & 3) * 8, &Vs[0][c2 * 512]);
            }
        }
        __syncthreads();

        int cur = 0;
        for (int j = jt0; j < jt1; j++) {
            const int key0 = j * KVB;
            if (j + 1 < jt1) {
                const int nk0 = key0 + KVB;
#pragma unroll
                for (int i = 0; i < 2; i++) {
                    int c2 = w * 2 + i;
                    int r7 = ((c2 & 1) << 2) | kr4;
                    int kcol = ((lane & 15) ^ r7) * 8;
                    GLOAD16(kgb + (nk0 + c2 * 4 + kr4) * HD + kcol, &Ks[cur ^ 1][c2 * 512]);
                    GLOAD16(vgb + (c2 * 16 + vr16) * T + nk0 + (lane & 3) * 8, &Vs[cur ^ 1][c2 * 512]);
                }
            }
            // ---- QK^T: S[16q][32k] per wave (swizzled K reads) ----
            f32x4 sv[2] = {};
            __builtin_amdgcn_s_setprio(1);
#pragma unroll
            for (int kt = 0; kt < 2; kt++) {
                int r = kt * 16 + lr;
                int rx = (r & 7) * 8;
#pragma unroll
                for (int kk = 0; kk < 4; kk++) {
                    short8 b = *reinterpret_cast<const short8*>(
                        &Ks[cur][r * HD + ((kk * 32 + lk) ^ rx)]);
                    sv[kt] = __builtin_amdgcn_mfma_f32_16x16x32_bf16(qf[kk], b, sv[kt], 0, 0, 0);
                }
            }
            __builtin_amdgcn_s_setprio(0);
            // ---- fixed-max softmax: p = exp(s*scale - 12), mask -> exp(-inf)=0 ----
            {
                int prow = g * 4;
#pragma unroll
                for (int rr = 0; rr < 4; rr++) {
                    int row = rowb + rr;
                    float v0 = (key0 + lr <= row) ? fmaf(sv[0][rr], scale, -12.f) : -1e30f;
                    float v1 = (key0 + 16 + lr <= row) ? fmaf(sv[1][rr], scale, -12.f) : -1e30f;
                    float p0 = __expf(v0);
                    float p1 = __expf(v1);
                    // truncation is sufficient for P in [0,1]
                    P[w][(prow + rr) * PLD + lr] = (short)(__float_as_uint(p0) >> 16);
                    P[w][(prow + rr) * PLD + 16 + lr] = (short)(__float_as_uint(p1) >> 16);
                }
            }
            // P is wave-private: compiler lgkmcnt ordering suffices, no barrier.
            short8 pa = *reinterpret_cast<const short8*>(&P[w][lr * PLD + lk]);
            // ---- PV: O[16q][128d] += P[16][32] * V[32][128]; l += P.1 ----
            __builtin_amdgcn_s_setprio(1);
            lacc = __builtin_amdgcn_mfma_f32_16x16x32_bf16(pa, kOnes, lacc, 0, 0, 0);
#pragma unroll
            for (int c = 0; c < 8; c++) {
                short8 bv = *reinterpret_cast<const short8*>(
                    &Vs[cur][(c * 16 + lr) * KVB + lk]);
                oacc[c] = __builtin_amdgcn_mfma_f32_16x16x32_bf16(pa, bv, oacc[c], 0, 0, 0);
            }
            __builtin_amdgcn_s_setprio(0);
            __syncthreads();   // drains staging vmcnt + protects dbuf reuse
            cur ^= 1;
        }
        // ---- emit unnormalized U (bf16) ----
        unsigned short* ub = U + ((size_t)(sp * NH + h) * T + rowb) * HD;
#pragma unroll
        for (int c = 0; c < 8; c++)
#pragma unroll
            for (int rr = 0; rr < 4; rr++)
                ub[rr * HD + c * 16 + lr] = (unsigned short)f2b(oacc[c][rr]);
    }
    // ---- stats: l per row (0 for empty splits; combine guards l>0) ----
    if (lr == 0) {
#pragma unroll
        for (int rr = 0; rr < 4; rr++)
            stats[(size_t)(sp * NH + h) * T + rowb + rr] = make_float2(12.f, lacc[rr]);
    }
}

// ---------------- combine: equal-weight merge of 4 splits -> Ob bf16 ----------------
__global__ __launch_bounds__(256) void combine_kernel(
    const unsigned int* __restrict__ U32, const float2* __restrict__ stats,
    short* __restrict__ Ob) {
    const int w = threadIdx.x >> 6;
    const int lane = threadIdx.x & 63;
    const int rid = blockIdx.x * 4 + w;      // h*T + t
    const int h = rid >> 11;
    const int tt = rid & (T - 1);
    float l[NSPLIT];
    float den = 0.f;
#pragma unroll
    for (int sp = 0; sp < NSPLIT; sp++) {
        l[sp] = stats[(size_t)sp * NH * T + rid].y;
        den += l[sp];
    }
    float inv = 1.0f / den;
    float o0 = 0.f, o1 = 0.f;
#pragma unroll
    for (int sp = 0; sp < NSPLIT; sp++) {
        if (l[sp] > 0.f) {   // wave-uniform branch (rid uniform per wave)
            unsigned int u = U32[((size_t)(sp * NH + h) * T + tt) * (HD / 2) + lane];
            o0 += b2f((unsigned short)(u & 0xffff));
            o1 += b2f((unsigned short)(u >> 16));
        }
    }
    o0 *= inv; o1 *= inv;
    unsigned int packed = ((unsigned int)(unsigned short)f2b(o1) << 16) |
                          (unsigned short)f2b(o0);
    reinterpret_cast<unsigned int*>(Ob)[tt * (HID / 2) + h * (HD / 2) + lane] = packed;
}

extern "C" void kernel_launch(void* const* d_in, const int* in_sizes, int n_in,
                              void* d_out, int out_size, void* d_ws, size_t ws_size,
                              hipStream_t stream) {
    const float* x = (const float*)d_in[0];
    const int* positions = (const int*)d_in[1];
    const int* qw_q = (const int*)d_in[2];
    const float* sc_q = (const float*)d_in[3];
    const int* qz_q = (const int*)d_in[4];
    const int* qw_k = (const int*)d_in[5];
    const float* sc_k = (const float*)d_in[6];
    const int* qz_k = (const int*)d_in[7];
    const int* qw_v = (const int*)d_in[8];
    const float* sc_v = (const float*)d_in[9];
    const int* qz_v = (const int*)d_in[10];
    const int* qw_o = (const int*)d_in[11];
    const float* sc_o = (const float*)d_in[12];
    const int* qz_o = (const int*)d_in[13];
    const float* qnw = (const float*)d_in[14];
    const float* knw = (const float*)d_in[15];
    float* out = (float*)d_out;

    char* ws = (char*)d_ws;
    short* Wqkv = (short*)(ws);                  // [3072][2048] bf16 (dead after QKV GEMM)
    short* Wo   = (short*)(ws + 12582912);       // [2048][2048] bf16 (live till end)
    short* xb   = (short*)(ws + 20971520);       // [2048][2048] bf16 (dead after QKV GEMM)
    float* qkv  = (float*)(ws + 29360128);       // [2048][3072] f32 (dead after normrope/vtrans)
    short* Qb   = (short*)(ws + 54525952);       // [2048][2048] bf16
    short* Kb   = (short*)(ws + 62914560);       // [4][2048][128] bf16
    short* Vt   = (short*)(ws + 65011712);       // [4][128][2048] bf16
    short* Ob   = (short*)(ws + 67108864);       // [2048][2048] bf16
    // reuse dead regions during attention:
    float2* stats   = (float2*)(ws);             // [4][16][2048] float2 = 1 MB (over Wqkv)
    unsigned short* U = (unsigned short*)(ws + 20971520); // [4][16][2048][128] bf16 = 32 MB (over xb+qkv)

    // zero split-K accumulation targets (async, graph-capture-safe)
    hipMemsetAsync(qkv, 0, (size_t)2048 * 3072 * sizeof(float), stream);
    hipMemsetAsync(out, 0, (size_t)out_size * sizeof(float), stream);

    dequant_kernel<<<(2048 * 256 + 255) / 256, 256, 0, stream>>>(qw_q, sc_q, qz_q, Wqkv, 2048, 2048);
    dequant_kernel<<<(512 * 256 + 255) / 256, 256, 0, stream>>>(qw_k, sc_k, qz_k, Wqkv + 2048 * 2048, 2048, 512);
    dequant_kernel<<<(512 * 256 + 255) / 256, 256, 0, stream>>>(qw_v, sc_v, qz_v, Wqkv + 2560 * 2048, 2048, 512);
    dequant_kernel<<<(2048 * 256 + 255) / 256, 256, 0, stream>>>(qw_o, sc_o, qz_o, Wo, 2048, 2048);

    cast_kernel<<<(524288 + 255) / 256, 256, 0, stream>>>(x, xb, 524288);

    dim3 g1(3072 / BN, 2048 / BM, 2);          // split-K=2: 768 blocks
    gemm_bt_splitk<<<g1, 256, 0, stream>>>(xb, Wqkv, qkv, 2048, 3072, 2048, 1024);

    dim3 g2(T, NH + NKH);
    normrope_kernel<<<g2, 128, 0, stream>>>(qkv, qnw, knw, positions, Qb, Kb);

    dim3 g3(T / 32, HD / 32, NKH);
    vtrans_kernel<<<g3, 256, 0, stream>>>(qkv, Vt);

    dim3 g4(T / QB, NH, NSPLIT);
    attn_split_kernel<<<g4, 256, 0, stream>>>(Qb, Kb, Vt, U, stats);

    combine_kernel<<<(T * NH) / 4, 256, 0, stream>>>((const unsigned int*)U, stats, Ob);

    dim3 g5(2048 / BN, 2048 / BM, 4);          // split-K=4: 1024 blocks
    gemm_bt_splitk<<<g5, 256, 0, stream>>>(Ob, Wo, out, 2048, 2048, 2048, 512);
}

// Round 9
// 180.290 us; speedup vs baseline: 1.4765x; 1.4765x over previous
//
#include <hip/hip_runtime.h>
#include <hip/hip_bf16.h>

#define T 2048
#define HID 2048
#define NH 16
#define NKH 4
#define HD 128
#define GSZ 128

typedef __attribute__((ext_vector_type(8))) short short8;
typedef __attribute__((ext_vector_type(4))) float f32x4;

#define GLOAD16(gp, lp) __builtin_amdgcn_global_load_lds( \
    (const __attribute__((address_space(1))) void*)(gp), \
    (__attribute__((address_space(3))) void*)(lp), 16, 0, 0)

__device__ inline short f2b(float f) {
    unsigned int u = __float_as_uint(f);
    unsigned int r = (u + 0x7fffu + ((u >> 16) & 1u)) >> 16;
    return (short)r;
}
__device__ inline float b2f(unsigned short u) {
    return __uint_as_float((unsigned int)u << 16);
}

// ---------------- dequant: int4 GPTQ -> bf16 W^T [N][K] ----------------
__global__ __launch_bounds__(256) void dequant_kernel(
    const int* __restrict__ qw, const float* __restrict__ sc,
    const int* __restrict__ qz, short* __restrict__ Wt, int K, int N) {
    int tid = blockIdx.x * blockDim.x + threadIdx.x;
    int K8 = K >> 3;
    if (tid >= N * K8) return;
    int n = tid / K8;
    int k8 = tid - n * K8;
    int q32 = qw[k8 * N + n];
    int g = (k8 << 3) / GSZ;
    float scale = sc[g * N + n];
    int z = (qz[g * (N >> 3) + (n >> 3)] >> ((n & 7) * 4)) & 15;
    float zf = (float)(z + 1);
    short8 out;
#pragma unroll
    for (int kk = 0; kk < 8; kk++) {
        int q = (q32 >> (kk * 4)) & 15;
        out[kk] = f2b(scale * ((float)q - zf));
    }
    *reinterpret_cast<short8*>(&Wt[n * K + (k8 << 3)]) = out;
}

// ---------------- cast x f32 -> bf16 ----------------
__global__ __launch_bounds__(256) void cast_kernel(
    const float* __restrict__ x, short* __restrict__ xb, int n8) {
    int i = blockIdx.x * blockDim.x + threadIdx.x;
    if (i >= n8) return;
    const float4* xp = reinterpret_cast<const float4*>(x) + i * 2;
    float4 a = xp[0], b = xp[1];
    short8 o;
    o[0] = f2b(a.x); o[1] = f2b(a.y); o[2] = f2b(a.z); o[3] = f2b(a.w);
    o[4] = f2b(b.x); o[5] = f2b(b.y); o[6] = f2b(b.z); o[7] = f2b(b.w);
    reinterpret_cast<short8*>(xb)[i] = o;
}

// -------- GEMM: C[M,N] f32 = A[M,K]bf16 * Bt[N,K]bf16^T  (128x64 tile) --------
// BN=64 doubles block count vs 128^2 (QKV: 768 blocks = 3/CU, O-proj: 512 = 2/CU)
// so inter-block overlap hides the 2-barrier stalls. LDS chunk-XOR swizzle
// (rule #21: linear gload_lds dest + pre-swizzled global col + XOR'd ds_read)
// kills the 16-way bank conflict of stride-128B fragment reads (was 9.4e6/disp).
#define BM 128
#define BN 64
#define BK 64

__global__ __launch_bounds__(256) void gemm_bt(
    const short* __restrict__ A, const short* __restrict__ Bt,
    float* __restrict__ C, int M, int N, int K) {
    __shared__ short As[BM * BK];   // 16 chunks of 512 elems
    __shared__ short Bs[BN * BK];   // 8 chunks
    const int t = threadIdx.x;
    const int lane = t & 63;
    const int w = t >> 6;
    const int bm = blockIdx.y * BM;
    const int bn = blockIdx.x * BN;
    const int wm = (w >> 1) * 64;   // 0 / 64
    const int wn = (w & 1) * 32;    // 0 / 32
    const int lr = lane & 15;
    const int lk = (lane >> 4) * 8;
    const int srow = lane >> 3;                    // row within 8-row chunk
    const int scol = ((lane & 7) ^ srow) * 8;      // pre-swizzled source col
    f32x4 acc[4][2] = {};
    for (int k0 = 0; k0 < K; k0 += BK) {
        __syncthreads();
#pragma unroll
        for (int i = 0; i < 4; i++) {
            int c = w * 4 + i;                     // A chunks 0..15
            GLOAD16(&A[(size_t)(bm + c * 8 + srow) * K + k0 + scol], &As[c * 512]);
        }
#pragma unroll
        for (int i = 0; i < 2; i++) {
            int c = w * 2 + i;                     // B chunks 0..7
            GLOAD16(&Bt[(size_t)(bn + c * 8 + srow) * K + k0 + scol], &Bs[c * 512]);
        }
        __syncthreads();
#pragma unroll
        for (int kc = 0; kc < 2; kc++) {
            short8 af[4], bf[2];
#pragma unroll
            for (int m = 0; m < 4; m++) {
                int r = wm + m * 16 + lr;
                af[m] = *reinterpret_cast<const short8*>(
                    &As[r * BK + ((kc * 32 + lk) ^ ((r & 7) * 8))]);
            }
#pragma unroll
            for (int n = 0; n < 2; n++) {
                int r = wn + n * 16 + lr;
                bf[n] = *reinterpret_cast<const short8*>(
                    &Bs[r * BK + ((kc * 32 + lk) ^ ((r & 7) * 8))]);
            }
#pragma unroll
            for (int m = 0; m < 4; m++)
#pragma unroll
                for (int n = 0; n < 2; n++)
                    acc[m][n] = __builtin_amdgcn_mfma_f32_16x16x32_bf16(
                        af[m], bf[n], acc[m][n], 0, 0, 0);
        }
    }
    const int rowb = bm + wm + (lane >> 4) * 4;
    const int colb = bn + wn + lr;
#pragma unroll
    for (int m = 0; m < 4; m++)
#pragma unroll
        for (int n = 0; n < 2; n++)
#pragma unroll
            for (int rr = 0; rr < 4; rr++)
                C[(size_t)(rowb + m * 16 + rr) * N + colb + n * 16] = acc[m][n][rr];
}

// ---------------- rmsnorm + rope ----------------
__global__ __launch_bounds__(128) void normrope_kernel(
    const float* __restrict__ qkv, const float* __restrict__ qw,
    const float* __restrict__ kw, const int* __restrict__ pos,
    short* __restrict__ Qb, short* __restrict__ Kb) {
    int tt = blockIdx.x;
    int hh = blockIdx.y;
    int d = threadIdx.x;
    bool isq = hh < NH;
    int h = isq ? hh : hh - NH;
    int off = isq ? h * HD : HID + h * HD;
    float x = qkv[tt * 3072 + off + d];
    float ss = x * x;
#pragma unroll
    for (int mask = 1; mask < 64; mask <<= 1) ss += __shfl_xor(ss, mask, 64);
    __shared__ float red[2];
    __shared__ float vals[HD];
    if ((d & 63) == 0) red[d >> 6] = ss;
    __syncthreads();
    float tot = red[0] + red[1];
    float r = rsqrtf(tot * (1.0f / HD) + 1e-6f);
    float wv = isq ? qw[d] : kw[d];
    float xn = x * r * wv;
    vals[d] = xn;
    __syncthreads();
    int p = pos[tt];
    int i = d & 63;
    float inv = exp2f(-(float)i * (13.287712379549449f / 64.0f));
    float ang = (float)p * inv;
    float c, s;
    sincosf(ang, &s, &c);
    float other = vals[d ^ 64];
    float out = (d < 64) ? (xn * c - other * s) : (xn * c + other * s);
    if (isq) Qb[tt * HID + h * HD + d] = f2b(out);
    else     Kb[(h * T + tt) * HD + d] = f2b(out);
}

// ---------------- V transpose: qkv f32 -> Vt[KH][HD][T] bf16 ----------------
__global__ __launch_bounds__(256) void vtrans_kernel(
    const float* __restrict__ qkv, short* __restrict__ Vt) {
    __shared__ float tile[32][33];
    int h = blockIdx.z;
    int d0 = blockIdx.y * 32;
    int t0 = blockIdx.x * 32;
    int tx = threadIdx.x & 31;
    int ty = threadIdx.x >> 5;
#pragma unroll
    for (int i = 0; i < 32; i += 8)
        tile[ty + i][tx] = qkv[(t0 + ty + i) * 3072 + 2560 + h * HD + d0 + tx];
    __syncthreads();
#pragma unroll
    for (int i = 0; i < 32; i += 8)
        Vt[(h * HD + d0 + ty + i) * T + t0 + tx] = f2b(tile[tx][ty + i]);
}

// ---------------- flash attention, split-K, FIXED-MAX softmax ----------------
// RMSNorm(w=1) bounds ||q||,||k|| <= sqrt(128); RoPE is a rotation ->
// every score s = q.k/sqrt(128) satisfies |s| <= sqrt(128) ~ 11.4 < 12.
// P = exp(s - 12): no running max, no rescale, no max reduction.
// Row-sum l via one extra MFMA against all-ones B. Combine: O = sum(U)/sum(l).
#define QB 64
#define KVB 32
#define NSPLIT 4
#define PLD 40   // P row stride in elems (80 B: 16B-aligned b128 rows)

__global__ __launch_bounds__(256) void attn_split_kernel(
    const short* __restrict__ Qb, const short* __restrict__ Kb,
    const short* __restrict__ Vt, unsigned short* __restrict__ U,
    float2* __restrict__ stats) {
    __shared__ short Ks[2][KVB * HD];   // [32][128], chunk-swizzled
    __shared__ short Vs[2][HD * KVB];   // [128][32], linear
    __shared__ short P[4][16 * PLD];
    const int t = threadIdx.x;
    const int lane = t & 63;
    const int w = t >> 6;
    const int h = blockIdx.y;
    const int sp = blockIdx.z;
    const int kvh = h >> 2;
    int bx = blockIdx.x;
    const int qt = (bx & 1) ? ((int)gridDim.x - 1 - (bx >> 1)) : (bx >> 1);
    const int qb0 = qt * QB;
    const int lr = lane & 15;
    const int g = lane >> 4;
    const int lk = g * 8;
    const int rowb = qb0 + w * 16 + g * 4;
    const int nt = (qt + 1) * 2;               // total 32-key tiles (causal window)
    const int len = (nt + NSPLIT - 1) / NSPLIT;
    int jt0 = sp * len; if (jt0 > nt) jt0 = nt;
    int jt1 = jt0 + len; if (jt1 > nt) jt1 = nt;

    f32x4 oacc[8] = {};
    f32x4 lacc = {};                           // row-sums via ones-MFMA
    const float scale = 0.08838834764831845f;  // 1/sqrt(128)
    short8 kOnes;
#pragma unroll
    for (int kk = 0; kk < 8; kk++) kOnes[kk] = (short)0x3F80;  // bf16 1.0

    if (jt0 < jt1) {
        short8 qf[4];
        {
            const short* qp = Qb + (qb0 + w * 16 + lr) * HID + h * HD + lk;
#pragma unroll
            for (int kk = 0; kk < 4; kk++)
                qf[kk] = *reinterpret_cast<const short8*>(qp + kk * 32);
        }
        const short* kgb = Kb + (size_t)(kvh * T) * HD;
        const short* vgb = Vt + (size_t)(kvh * HD) * T;
        const int kr4 = lane >> 4;            // K stage: row within 4-row group
        const int vr16 = lane >> 2;           // V stage: row within 16-row group

        // prologue: stage tile jt0 into buf 0
        {
            const int key0 = jt0 * KVB;
#pragma unroll
            for (int i = 0; i < 2; i++) {
                int c2 = w * 2 + i;
                int r7 = ((c2 & 1) << 2) | kr4;
                int kcol = ((lane & 15) ^ r7) * 8;
                GLOAD16(kgb + (key0 + c2 * 4 + kr4) * HD + kcol, &Ks[0][c2 * 512]);
                GLOAD16(vgb + (c2 * 16 + vr16) * T + key0 + (lane & 3) * 8, &Vs[0][c2 * 512]);
            }
        }
        __syncthreads();

        int cur = 0;
        for (int j = jt0; j < jt1; j++) {
            const int key0 = j * KVB;
            if (j + 1 < jt1) {
                const int nk0 = key0 + KVB;
#pragma unroll
                for (int i = 0; i < 2; i++) {
                    int c2 = w * 2 + i;
                    int r7 = ((c2 & 1) << 2) | kr4;
                    int kcol = ((lane & 15) ^ r7) * 8;
                    GLOAD16(kgb + (nk0 + c2 * 4 + kr4) * HD + kcol, &Ks[cur ^ 1][c2 * 512]);
                    GLOAD16(vgb + (c2 * 16 + vr16) * T + nk0 + (lane & 3) * 8, &Vs[cur ^ 1][c2 * 512]);
                }
            }
            // ---- QK^T: S[16q][32k] per wave (swizzled K reads) ----
            f32x4 sv[2] = {};
            __builtin_amdgcn_s_setprio(1);
#pragma unroll
            for (int kt = 0; kt < 2; kt++) {
                int r = kt * 16 + lr;
                int rx = (r & 7) * 8;
#pragma unroll
                for (int kk = 0; kk < 4; kk++) {
                    short8 b = *reinterpret_cast<const short8*>(
                        &Ks[cur][r * HD + ((kk * 32 + lk) ^ rx)]);
                    sv[kt] = __builtin_amdgcn_mfma_f32_16x16x32_bf16(qf[kk], b, sv[kt], 0, 0, 0);
                }
            }
            __builtin_amdgcn_s_setprio(0);
            // ---- fixed-max softmax: p = exp(s*scale - 12), mask -> exp(-inf)=0 ----
            {
                int prow = g * 4;
#pragma unroll
                for (int rr = 0; rr < 4; rr++) {
                    int row = rowb + rr;
                    float v0 = (key0 + lr <= row) ? fmaf(sv[0][rr], scale, -12.f) : -1e30f;
                    float v1 = (key0 + 16 + lr <= row) ? fmaf(sv[1][rr], scale, -12.f) : -1e30f;
                    float p0 = __expf(v0);
                    float p1 = __expf(v1);
                    // truncation is sufficient for P in [0,1]
                    P[w][(prow + rr) * PLD + lr] = (short)(__float_as_uint(p0) >> 16);
                    P[w][(prow + rr) * PLD + 16 + lr] = (short)(__float_as_uint(p1) >> 16);
                }
            }
            // P is wave-private: compiler lgkmcnt ordering suffices, no barrier.
            short8 pa = *reinterpret_cast<const short8*>(&P[w][lr * PLD + lk]);
            // ---- PV: O[16q][128d] += P[16][32] * V[32][128]; l += P.1 ----
            __builtin_amdgcn_s_setprio(1);
            lacc = __builtin_amdgcn_mfma_f32_16x16x32_bf16(pa, kOnes, lacc, 0, 0, 0);
#pragma unroll
            for (int c = 0; c < 8; c++) {
                short8 bv = *reinterpret_cast<const short8*>(
                    &Vs[cur][(c * 16 + lr) * KVB + lk]);
                oacc[c] = __builtin_amdgcn_mfma_f32_16x16x32_bf16(pa, bv, oacc[c], 0, 0, 0);
            }
            __builtin_amdgcn_s_setprio(0);
            __syncthreads();   // drains staging vmcnt + protects dbuf reuse
            cur ^= 1;
        }
        // ---- emit unnormalized U (bf16) ----
        unsigned short* ub = U + ((size_t)(sp * NH + h) * T + rowb) * HD;
#pragma unroll
        for (int c = 0; c < 8; c++)
#pragma unroll
            for (int rr = 0; rr < 4; rr++)
                ub[rr * HD + c * 16 + lr] = (unsigned short)f2b(oacc[c][rr]);
    }
    // ---- stats: l per row (0 for empty splits; combine guards l>0) ----
    if (lr == 0) {
#pragma unroll
        for (int rr = 0; rr < 4; rr++)
            stats[(size_t)(sp * NH + h) * T + rowb + rr] = make_float2(12.f, lacc[rr]);
    }
}

// ---------------- combine: equal-weight merge of 4 splits -> Ob bf16 ----------------
__global__ __launch_bounds__(256) void combine_kernel(
    const unsigned int* __restrict__ U32, const float2* __restrict__ stats,
    short* __restrict__ Ob) {
    const int w = threadIdx.x >> 6;
    const int lane = threadIdx.x & 63;
    const int rid = blockIdx.x * 4 + w;      // h*T + t
    const int h = rid >> 11;
    const int tt = rid & (T - 1);
    float l[NSPLIT];
    float den = 0.f;
#pragma unroll
    for (int sp = 0; sp < NSPLIT; sp++) {
        l[sp] = stats[(size_t)sp * NH * T + rid].y;
        den += l[sp];
    }
    float inv = 1.0f / den;
    float o0 = 0.f, o1 = 0.f;
#pragma unroll
    for (int sp = 0; sp < NSPLIT; sp++) {
        if (l[sp] > 0.f) {   // wave-uniform branch (rid uniform per wave)
            unsigned int u = U32[((size_t)(sp * NH + h) * T + tt) * (HD / 2) + lane];
            o0 += b2f((unsigned short)(u & 0xffff));
            o1 += b2f((unsigned short)(u >> 16));
        }
    }
    o0 *= inv; o1 *= inv;
    unsigned int packed = ((unsigned int)(unsigned short)f2b(o1) << 16) |
                          (unsigned short)f2b(o0);
    reinterpret_cast<unsigned int*>(Ob)[tt * (HID / 2) + h * (HD / 2) + lane] = packed;
}

extern "C" void kernel_launch(void* const* d_in, const int* in_sizes, int n_in,
                              void* d_out, int out_size, void* d_ws, size_t ws_size,
                              hipStream_t stream) {
    const float* x = (const float*)d_in[0];
    const int* positions = (const int*)d_in[1];
    const int* qw_q = (const int*)d_in[2];
    const float* sc_q = (const float*)d_in[3];
    const int* qz_q = (const int*)d_in[4];
    const int* qw_k = (const int*)d_in[5];
    const float* sc_k = (const float*)d_in[6];
    const int* qz_k = (const int*)d_in[7];
    const int* qw_v = (const int*)d_in[8];
    const float* sc_v = (const float*)d_in[9];
    const int* qz_v = (const int*)d_in[10];
    const int* qw_o = (const int*)d_in[11];
    const float* sc_o = (const float*)d_in[12];
    const int* qz_o = (const int*)d_in[13];
    const float* qnw = (const float*)d_in[14];
    const float* knw = (const float*)d_in[15];
    float* out = (float*)d_out;

    char* ws = (char*)d_ws;
    short* Wqkv = (short*)(ws);                  // [3072][2048] bf16 (dead after QKV GEMM)
    short* Wo   = (short*)(ws + 12582912);       // [2048][2048] bf16 (live till end)
    short* xb   = (short*)(ws + 20971520);       // [2048][2048] bf16 (dead after QKV GEMM)
    float* qkv  = (float*)(ws + 29360128);       // [2048][3072] f32 (dead after normrope/vtrans)
    short* Qb   = (short*)(ws + 54525952);       // [2048][2048] bf16
    short* Kb   = (short*)(ws + 62914560);       // [4][2048][128] bf16
    short* Vt   = (short*)(ws + 65011712);       // [4][128][2048] bf16
    short* Ob   = (short*)(ws + 67108864);       // [2048][2048] bf16
    // reuse dead regions during attention:
    float2* stats   = (float2*)(ws);             // [4][16][2048] float2 = 1 MB (over Wqkv)
    unsigned short* U = (unsigned short*)(ws + 20971520); // [4][16][2048][128] bf16 = 32 MB (over xb+qkv)

    dequant_kernel<<<(2048 * 256 + 255) / 256, 256, 0, stream>>>(qw_q, sc_q, qz_q, Wqkv, 2048, 2048);
    dequant_kernel<<<(512 * 256 + 255) / 256, 256, 0, stream>>>(qw_k, sc_k, qz_k, Wqkv + 2048 * 2048, 2048, 512);
    dequant_kernel<<<(512 * 256 + 255) / 256, 256, 0, stream>>>(qw_v, sc_v, qz_v, Wqkv + 2560 * 2048, 2048, 512);
    dequant_kernel<<<(2048 * 256 + 255) / 256, 256, 0, stream>>>(qw_o, sc_o, qz_o, Wo, 2048, 2048);

    cast_kernel<<<(524288 + 255) / 256, 256, 0, stream>>>(x, xb, 524288);

    dim3 g1(3072 / BN, 2048 / BM);               // 48 x 16 = 768 blocks
    gemm_bt<<<g1, 256, 0, stream>>>(xb, Wqkv, qkv, 2048, 3072, 2048);

    dim3 g2(T, NH + NKH);
    normrope_kernel<<<g2, 128, 0, stream>>>(qkv, qnw, knw, positions, Qb, Kb);

    dim3 g3(T / 32, HD / 32, NKH);
    vtrans_kernel<<<g3, 256, 0, stream>>>(qkv, Vt);

    dim3 g4(T / QB, NH, NSPLIT);
    attn_split_kernel<<<g4, 256, 0, stream>>>(Qb, Kb, Vt, U, stats);

    combine_kernel<<<(T * NH) / 4, 256, 0, stream>>>((const unsigned int*)U, stats, Ob);

    dim3 g5(2048 / BN, 2048 / BM);               // 32 x 16 = 512 blocks
    gemm_bt<<<g5, 256, 0, stream>>>(Ob, Wo, out, 2048, 2048, 2048);
}